// Round 1
// baseline (29.710 us; speedup 1.0000x reference)
//
#include <hip/hip_runtime.h>

// MedianPool: x (32, 4096, 128) f32, window=5, circular pad along dim 1,
// lower median (sorted[2] of 5). Output f32 same shape.

constexpr int B  = 32;
constexpr int L  = 4096;   // power of two -> wrap via mask
constexpr int C  = 128;
constexpr int C4 = C / 4;  // float4 per row = 32

__device__ __forceinline__ float4 f4min(float4 a, float4 b) {
    return make_float4(fminf(a.x, b.x), fminf(a.y, b.y),
                       fminf(a.z, b.z), fminf(a.w, b.w));
}
__device__ __forceinline__ float4 f4max(float4 a, float4 b) {
    return make_float4(fmaxf(a.x, b.x), fmaxf(a.y, b.y),
                       fmaxf(a.z, b.z), fmaxf(a.w, b.w));
}

#define SORT2(x, y) { float4 _lo = f4min(x, y); float4 _hi = f4max(x, y); (x) = _lo; (y) = _hi; }

__global__ __launch_bounds__(256)
void MedianPool_73426760893099_kernel(const float4* __restrict__ x,
                                      float4* __restrict__ out) {
    const int idx = blockIdx.x * blockDim.x + threadIdx.x;  // over B*L*C4 = 4194304
    const int c4 = idx & (C4 - 1);
    const int l  = (idx >> 5) & (L - 1);
    const int b  = idx >> 17;  // idx / (L*C4)

    const float4* __restrict__ xb = x + (size_t)b * L * C4;

    // Circular window rows: (l+i) mod L, L power of two.
    const int l0 = l;
    const int l1 = (l + 1) & (L - 1);
    const int l2 = (l + 2) & (L - 1);
    const int l3 = (l + 3) & (L - 1);
    const int l4 = (l + 4) & (L - 1);

    float4 v0 = xb[(size_t)l0 * C4 + c4];
    float4 v1 = xb[(size_t)l1 * C4 + c4];
    float4 v2 = xb[(size_t)l2 * C4 + c4];
    float4 v3 = xb[(size_t)l3 * C4 + c4];
    float4 v4 = xb[(size_t)l4 * C4 + c4];

    // Optimal 9-comparator sorting network for n=5 (depth 5):
    // (0,1)(3,4) (2,4) (2,3)(1,4) (0,3) (0,2)(1,3) (1,2)
    SORT2(v0, v1);
    SORT2(v3, v4);
    SORT2(v2, v4);
    SORT2(v2, v3);
    SORT2(v1, v4);
    SORT2(v0, v3);
    SORT2(v0, v2);
    SORT2(v1, v3);
    SORT2(v1, v2);
    // v2 now holds sorted[2] = lower median.

    out[idx] = v2;
}

extern "C" void kernel_launch(void* const* d_in, const int* in_sizes, int n_in,
                              void* d_out, int out_size, void* d_ws, size_t ws_size,
                              hipStream_t stream) {
    const float4* x   = (const float4*)d_in[0];
    float4*       out = (float4*)d_out;

    const int total4 = B * L * C4;            // 4,194,304 float4 elements
    const int block  = 256;
    const int grid   = total4 / block;        // 16384
    MedianPool_73426760893099_kernel<<<grid, block, 0, stream>>>(x, out);
}

// Round 3
// 26.107 us; speedup vs baseline: 1.1380x; 1.1380x over previous
//
#include <hip/hip_runtime.h>

// MedianPool: x (32, 4096, 128) f32, window=5, circular pad along dim 1,
// lower median (sorted[2] of 5). Output f32 same shape.
//
// R2: same as R1 (4 output rows/thread, 8 row loads, nontemporal stores) but
// using clang native ext_vector_type(4) so __builtin_nontemporal_store accepts it.

constexpr int B   = 32;
constexpr int L   = 4096;    // power of two -> wrap via mask
constexpr int C   = 128;
constexpr int C4  = C / 4;   // float4 per row = 32
constexpr int RPT = 4;       // output rows per thread
constexpr int LG  = L / RPT; // 1024 row-groups per batch

typedef float f32x4 __attribute__((ext_vector_type(4)));

__device__ __forceinline__ f32x4 f4min(f32x4 a, f32x4 b) {
    f32x4 r;
    r.x = fminf(a.x, b.x); r.y = fminf(a.y, b.y);
    r.z = fminf(a.z, b.z); r.w = fminf(a.w, b.w);
    return r;
}
__device__ __forceinline__ f32x4 f4max(f32x4 a, f32x4 b) {
    f32x4 r;
    r.x = fmaxf(a.x, b.x); r.y = fmaxf(a.y, b.y);
    r.z = fmaxf(a.z, b.z); r.w = fmaxf(a.w, b.w);
    return r;
}

#define SORT2(x, y) { f32x4 _lo = f4min(x, y); f32x4 _hi = f4max(x, y); (x) = _lo; (y) = _hi; }

// Lower median of 5 via optimal 9-comparator network; returns sorted[2].
__device__ __forceinline__ f32x4 median5(f32x4 v0, f32x4 v1, f32x4 v2,
                                         f32x4 v3, f32x4 v4) {
    SORT2(v0, v1);
    SORT2(v3, v4);
    SORT2(v2, v4);
    SORT2(v2, v3);
    SORT2(v1, v4);
    SORT2(v0, v3);
    SORT2(v0, v2);
    SORT2(v1, v3);
    SORT2(v1, v2);
    return v2;
}

__global__ __launch_bounds__(256)
void MedianPool_73426760893099_kernel(const f32x4* __restrict__ x,
                                      f32x4* __restrict__ out) {
    const int idx = blockIdx.x * blockDim.x + threadIdx.x;  // over B*LG*C4 = 1,048,576
    const int c4 = idx & (C4 - 1);
    const int lg = (idx >> 5) & (LG - 1);
    const int b  = idx >> 15;   // idx / (LG*C4)

    const f32x4* __restrict__ xb = x + (size_t)b * L * C4;
    const int l0 = lg * RPT;

    // Load RPT + 4 = 8 rows (circular).
    f32x4 r0 = xb[(size_t)((l0 + 0) & (L - 1)) * C4 + c4];
    f32x4 r1 = xb[(size_t)((l0 + 1) & (L - 1)) * C4 + c4];
    f32x4 r2 = xb[(size_t)((l0 + 2) & (L - 1)) * C4 + c4];
    f32x4 r3 = xb[(size_t)((l0 + 3) & (L - 1)) * C4 + c4];
    f32x4 r4 = xb[(size_t)((l0 + 4) & (L - 1)) * C4 + c4];
    f32x4 r5 = xb[(size_t)((l0 + 5) & (L - 1)) * C4 + c4];
    f32x4 r6 = xb[(size_t)((l0 + 6) & (L - 1)) * C4 + c4];
    f32x4 r7 = xb[(size_t)((l0 + 7) & (L - 1)) * C4 + c4];

    f32x4 m0 = median5(r0, r1, r2, r3, r4);
    f32x4 m1 = median5(r1, r2, r3, r4, r5);
    f32x4 m2 = median5(r2, r3, r4, r5, r6);
    f32x4 m3 = median5(r3, r4, r5, r6, r7);

    f32x4* o = out + (size_t)b * L * C4 + (size_t)l0 * C4 + c4;
    __builtin_nontemporal_store(m0, o + 0 * C4);
    __builtin_nontemporal_store(m1, o + 1 * C4);
    __builtin_nontemporal_store(m2, o + 2 * C4);
    __builtin_nontemporal_store(m3, o + 3 * C4);
}

extern "C" void kernel_launch(void* const* d_in, const int* in_sizes, int n_in,
                              void* d_out, int out_size, void* d_ws, size_t ws_size,
                              hipStream_t stream) {
    const f32x4* x   = (const f32x4*)d_in[0];
    f32x4*       out = (f32x4*)d_out;

    const int threads = B * LG * C4;          // 1,048,576
    const int block   = 256;
    const int grid    = threads / block;      // 4096
    MedianPool_73426760893099_kernel<<<grid, block, 0, stream>>>(x, out);
}

// Round 4
// 24.006 us; speedup vs baseline: 1.2376x; 1.0875x over previous
//
#include <hip/hip_runtime.h>

// MedianPool: x (32, 4096, 128) f32, window=5, circular pad along dim 1,
// lower median (sorted[2] of 5). Output f32 same shape.
//
// R3: RPT=8 (12 row loads -> 8 medians, 1.5x load amplification),
// 7-op median-of-5 via v_med3_f32, XCD-contiguous block swizzle,
// nontemporal f32x4 stores.

constexpr int B   = 32;
constexpr int L   = 4096;    // power of two -> wrap via mask
constexpr int C   = 128;
constexpr int C4  = C / 4;   // f32x4 per row = 32
constexpr int RPT = 8;       // output rows per thread
constexpr int LG  = L / RPT; // 512 row-groups per batch
constexpr int NXCD = 8;

typedef float f32x4 __attribute__((ext_vector_type(4)));

__device__ __forceinline__ f32x4 f4min(f32x4 a, f32x4 b) {
    f32x4 r;
    r.x = fminf(a.x, b.x); r.y = fminf(a.y, b.y);
    r.z = fminf(a.z, b.z); r.w = fminf(a.w, b.w);
    return r;
}
__device__ __forceinline__ f32x4 f4max(f32x4 a, f32x4 b) {
    f32x4 r;
    r.x = fmaxf(a.x, b.x); r.y = fmaxf(a.y, b.y);
    r.z = fmaxf(a.z, b.z); r.w = fmaxf(a.w, b.w);
    return r;
}
__device__ __forceinline__ f32x4 f4med3(f32x4 a, f32x4 b, f32x4 c) {
    f32x4 r;
    r.x = __builtin_amdgcn_fmed3f(a.x, b.x, c.x);
    r.y = __builtin_amdgcn_fmed3f(a.y, b.y, c.y);
    r.z = __builtin_amdgcn_fmed3f(a.z, b.z, c.z);
    r.w = __builtin_amdgcn_fmed3f(a.w, b.w, c.w);
    return r;
}

// Lower median of 5, 7 ops: the min of the two pair-minima has rank <= 2,
// the max of the two pair-maxima has rank >= 4 -> discard both; median of
// the 3 survivors is the answer.
__device__ __forceinline__ f32x4 median5(f32x4 a, f32x4 b, f32x4 c,
                                         f32x4 d, f32x4 e) {
    f32x4 t1 = f4min(a, b), t2 = f4max(a, b);
    f32x4 t3 = f4min(c, d), t4 = f4max(c, d);
    f32x4 t5 = f4max(t1, t3);
    f32x4 t6 = f4min(t2, t4);
    return f4med3(t5, t6, e);
}

__global__ __launch_bounds__(256)
void MedianPool_73426760893099_kernel(const f32x4* __restrict__ x,
                                      f32x4* __restrict__ out) {
    // XCD-contiguous swizzle: nwg = 2048, divisible by 8. HW assigns
    // blockIdx round-robin across XCDs; remap so each XCD owns a
    // contiguous chunk of row-groups (overlap rows then share an L2).
    const int nwg  = gridDim.x;
    const int cpx  = nwg / NXCD;
    const int bid  = (int)blockIdx.x;
    const int bsw  = (bid % NXCD) * cpx + bid / NXCD;

    const int idx = bsw * blockDim.x + threadIdx.x;  // over B*LG*C4 = 524,288
    const int c4 = idx & (C4 - 1);
    const int lg = (idx >> 5) & (LG - 1);
    const int b  = idx >> 14;   // idx / (LG*C4)

    const f32x4* __restrict__ xb = x + (size_t)b * L * C4;
    const int l0 = lg * RPT;

    // Load RPT + 4 = 12 rows (circular).
    f32x4 r[RPT + 4];
#pragma unroll
    for (int i = 0; i < RPT + 4; ++i)
        r[i] = xb[(size_t)((l0 + i) & (L - 1)) * C4 + c4];

    f32x4* o = out + (size_t)b * L * C4 + (size_t)l0 * C4 + c4;
#pragma unroll
    for (int i = 0; i < RPT; ++i) {
        f32x4 m = median5(r[i], r[i + 1], r[i + 2], r[i + 3], r[i + 4]);
        __builtin_nontemporal_store(m, o + i * C4);
    }
}

extern "C" void kernel_launch(void* const* d_in, const int* in_sizes, int n_in,
                              void* d_out, int out_size, void* d_ws, size_t ws_size,
                              hipStream_t stream) {
    const f32x4* x   = (const f32x4*)d_in[0];
    f32x4*       out = (f32x4*)d_out;

    const int threads = B * LG * C4;          // 524,288
    const int block   = 256;
    const int grid    = threads / block;      // 2048
    MedianPool_73426760893099_kernel<<<grid, block, 0, stream>>>(x, out);
}